// Round 13
// baseline (231.036 us; speedup 1.0000x reference)
//
#include <hip/hip_runtime.h>
#include <cstdint>
#include <cstddef>

// ---------- types / helpers ----------
typedef __bf16 bf16x8 __attribute__((ext_vector_type(8)));
typedef float  f32x4  __attribute__((ext_vector_type(4)));
typedef unsigned short us;

#define DEV static __device__ __forceinline__

DEV us f2bf(float f) {
    unsigned int u = __builtin_bit_cast(unsigned int, f);
    u += 0x7FFFu + ((u >> 16) & 1u);   // RNE
    return (us)(u >> 16);
}
DEV unsigned int pack2bf(float a, float b) {   // [lo=a, hi=b], round-half-up (cheap)
    unsigned int ua = __builtin_bit_cast(unsigned int, a) + 0x8000u;
    unsigned int ub = __builtin_bit_cast(unsigned int, b) + 0x8000u;
    return (ua >> 16) | (ub & 0xFFFF0000u);    // -> v_perm_b32
}

DEV void gll16(const void* g, void* l) {   // 16B global->LDS direct (wave: +lane*16)
    __builtin_amdgcn_global_load_lds(
        (const __attribute__((address_space(1))) unsigned int*)g,
        (__attribute__((address_space(3))) unsigned int*)l, 16, 0, 0);
}

DEV bf16x8 ld_frag(const us* p) {
    return __builtin_bit_cast(bf16x8, *reinterpret_cast<const uint4*>(p));
}

// ---------- problem constants ----------
#define BB 4
#define TT 2048
#define CC 768
#define NH 12
#define DH 64
#define MM (BB*TT)          // 8192
#define QSCALE 0.1803368801111144f   // 0.125 * log2(e): softmax via exp2

// ---------- fused prep: cast x->bf16 | transpose w_attn | transpose w_proj ----------
#define PREP_CAST_BLK 1024
#define PREP_TA_BLK   ((3*CC/32)*(CC/32))   // 72*24 = 1728
#define PREP_TP_BLK   ((CC/32)*(CC/32))     // 24*24 = 576

__global__ __launch_bounds__(256)
void prep_k(const float* __restrict__ x, us* __restrict__ xb,
            const float* __restrict__ wA, us* __restrict__ wAt,
            const float* __restrict__ wP, us* __restrict__ wPt)
{
    const int bid = blockIdx.x;
    const int tid = threadIdx.x;

    if (bid < PREP_CAST_BLK) {
        const int n4 = MM * CC / 4;
        int i = bid * 256 + tid;
        const int stride = PREP_CAST_BLK * 256;
        for (; i < n4; i += stride) {
            float4 f = reinterpret_cast<const float4*>(x)[i];
            ushort4 o;
            o.x = f2bf(f.x); o.y = f2bf(f.y); o.z = f2bf(f.z); o.w = f2bf(f.w);
            reinterpret_cast<ushort4*>(xb)[i] = o;
        }
        return;
    }

    // transpose path: dst[Cc][R] = bf16(src[R][Cc]), 32x32 tiles, threads (32,8)
    __shared__ float tile[32][33];
    const float* src; us* dst; int R, Cc, tb;
    if (bid < PREP_CAST_BLK + PREP_TA_BLK) {
        src = wA; dst = wAt; R = CC; Cc = 3 * CC; tb = bid - PREP_CAST_BLK;
    } else {
        src = wP; dst = wPt; R = CC; Cc = CC;     tb = bid - PREP_CAST_BLK - PREP_TA_BLK;
    }
    const int gx = Cc / 32;
    const int c0 = (tb % gx) * 32, r0 = (tb / gx) * 32;
    const int tx = tid & 31, ty = tid >> 5;
#pragma unroll
    for (int i = 0; i < 4; ++i)
        tile[ty + i*8][tx] = src[(size_t)(r0 + ty + i*8) * Cc + c0 + tx];
    __syncthreads();
#pragma unroll
    for (int i = 0; i < 4; ++i)
        dst[(size_t)(c0 + ty + i*8) * R + r0 + tx] = f2bf(tile[tx][ty + i*8]);
}

// ---------- fraglet layouts ----------
// K: offK(t,d) = (t>>4)*1024 + ((d>>3)&7)*128 + (t&15)*8 + (d&7)
//    frag (j,sub,hh): addr = (j*4+sub)*1024 + hh*512 + lane*8
// V: offV(d,t) = (t>>6)*4096 + ((d>>4)&3)*1024 + ((t>>3)&7)*128 + (d&15)*8 + (t&7)
//    frag (j,dsub,kc): addr = j*4096 + dsub*1024 + kc*512 + lane*8
// Both bijective on [0, TT*DH).

// ---------- GEMM: C[M,N] = A[M,K](bf16) * Bt[N,K]^T + bias[N] ----------
// 2-phase double-buffered staging + XCD-chunked block swizzle (kept from R12:
// inferred -2.6us). MODE 0: f32 Cout | MODE 1: scatter Q / K-fraglet / V-fraglet
#define BM 128
#define BN 128
#define BK 32

template<int MODE>
__global__ __launch_bounds__(256)
void gemm_bt(const us* __restrict__ A,
             const us* __restrict__ Bt,
             const float* __restrict__ bias,
             float* __restrict__ Cout,
             us* __restrict__ Qo, us* __restrict__ Ko, us* __restrict__ Vo,
             int M, int N, int K)
{
    __shared__ __align__(16) us As[2][BM * BK];
    __shared__ __align__(16) us Bs[2][BN * BK];

    const int tid  = threadIdx.x;
    const int wave = tid >> 6, lane = tid & 63;
    const int quad = lane >> 4, l16 = lane & 15;
    const int waveM = (wave >> 1) * 64, waveN = (wave & 1) * 64;

    // XCD-chunked swizzle (bijective: gridDim.x % 8 == 0)
    const int nxt   = N / BN;
    const int chunk = gridDim.x >> 3;
    const int lid   = blockIdx.x;
    const int swz   = (lid & 7) * chunk + (lid >> 3);
    const int m0 = (swz / nxt) * BM, n0 = (swz % nxt) * BN;

    const f32x4 zero4 = {0.f, 0.f, 0.f, 0.f};
    f32x4 acc[4][4];
#pragma unroll
    for (int i = 0; i < 4; ++i)
#pragma unroll
        for (int j = 0; j < 4; ++j) acc[i][j] = zero4;

    const int lrow = lane >> 2, lch = (lane & 3) * 8;
    const int nk = K / BK;

    auto STAGE = [&](int buf, int kt) {
#pragma unroll
        for (int c = 0; c < 2; ++c) {
            int rb = (wave * 2 + c) * 16;
            int row = rb + lrow;
            gll16(A  + (size_t)(m0 + row) * K + kt * BK + lch, &As[buf][rb * BK]);
            gll16(Bt + (size_t)(n0 + row) * K + kt * BK + lch, &Bs[buf][rb * BK]);
        }
    };

    STAGE(0, 0);
    __syncthreads();                    // vmcnt(0) drain: buf0 ready
    int cur = 0;

    for (int kt = 0; kt < nk; ++kt) {
        if (kt + 1 < nk) STAGE(cur ^ 1, kt + 1);   // prefetch into other buffer

        bf16x8 af[4], bfv[4];
#pragma unroll
        for (int mi = 0; mi < 4; ++mi)
            af[mi] = *reinterpret_cast<const bf16x8*>(&As[cur][(waveM + mi * 16 + l16) * BK + quad * 8]);
#pragma unroll
        for (int ni = 0; ni < 4; ++ni)
            bfv[ni] = *reinterpret_cast<const bf16x8*>(&Bs[cur][(waveN + ni * 16 + l16) * BK + quad * 8]);
#pragma unroll
        for (int mi = 0; mi < 4; ++mi)
#pragma unroll
            for (int ni = 0; ni < 4; ++ni)
                acc[mi][ni] = __builtin_amdgcn_mfma_f32_16x16x32_bf16(af[mi], bfv[ni], acc[mi][ni], 0, 0, 0);

        __syncthreads();
        cur ^= 1;
    }

    // epilogue: C/D layout col = l16, row = quad*4 + reg
#pragma unroll
    for (int mi = 0; mi < 4; ++mi) {
#pragma unroll
        for (int ni = 0; ni < 4; ++ni) {
            int n = n0 + waveN + ni * 16 + l16;
            float bv = bias[n];
            int mg = m0 + waveM + mi * 16 + quad * 4;   // first of 4 consecutive m
            if (MODE == 0) {
#pragma unroll
                for (int reg = 0; reg < 4; ++reg)
                    Cout[(size_t)(mg + reg) * N + n] = acc[mi][ni][reg] + bv;
            } else {
                int which = n / CC, c2 = n % CC;
                int h = c2 >> 6, d = c2 & 63;
                int b = mg >> 11, t0 = mg & 2047;
                size_t hb = (size_t)(b * NH + h) * TT * DH;
                if (which == 2) {
                    // V fraglet: 4 consecutive t stay contiguous -> one 8B store
                    size_t off = hb + (size_t)(t0 >> 6) * 4096 + (d >> 4) * 1024
                               + ((t0 >> 3) & 7) * 128 + (d & 15) * 8 + (t0 & 7);
                    ushort4 pk;
                    pk.x = f2bf(acc[mi][ni][0] + bv);
                    pk.y = f2bf(acc[mi][ni][1] + bv);
                    pk.z = f2bf(acc[mi][ni][2] + bv);
                    pk.w = f2bf(acc[mi][ni][3] + bv);
                    *reinterpret_cast<ushort4*>(Vo + off) = pk;
                } else if (which == 1) {
                    // K fraglet: per-reg scalar store, stride 8 elems
                    size_t off = hb + (size_t)(t0 >> 4) * 1024 + (d >> 3) * 128
                               + (t0 & 15) * 8 + (d & 7);
#pragma unroll
                    for (int reg = 0; reg < 4; ++reg)
                        Ko[off + reg * 8] = f2bf(acc[mi][ni][reg] + bv);
                } else {
#pragma unroll
                    for (int reg = 0; reg < 4; ++reg) {
                        size_t off = hb + (size_t)(t0 + reg) * DH + d;
                        Qo[off] = f2bf((acc[mi][ni][reg] + bv) * QSCALE);
                    }
                }
            }
        }
    }
}

// ---------- flash attention: R11 verified path + unroll-2 tile loop ----------
// 768 blocks x 2 waves, pair {pw,63-pw}, 33 tiles/wave, fraglet loads,
// fixed-shift softmax, deferred l-reduce, P LDS round-trip (R12 proved the
// round-trip is NOT on the critical path - register-direct PV was slower).
// SINGLE CHANGE vs R11: #pragma unroll 2 on the key-tile loop. Both unrolled
// iterations' 16 loads live in ONE scheduling region with no loop-carried
// state (R9's failure mode), so the list scheduler can hoist tile j+1's
// independent global loads above tile j's compute. Expected evidence:
// VGPR 112 -> ~160-200 if hoisting happened.
#define PST 72

__global__ __launch_bounds__(128)
void attn_k(const us* __restrict__ Qg,
            const us* __restrict__ Kg,   // fraglet layout
            const us* __restrict__ Vt,   // fraglet layout
            us* __restrict__ Og)
{
    __shared__ __align__(16) us Ps[2][32 * PST];   // per-wave P[g*16+m][key]

    const int tid  = threadIdx.x;
    const int wave = tid >> 6, lane = tid & 63;
    const int quad = lane >> 4, l16 = lane & 15;

    // XCD-locality decode: xcd = id%8 (round-robin dispatch heuristic)
    const int id  = blockIdx.x;
    const int xcd = id & 7, s = id >> 3;           // s in 0..95
    const int bh  = xcd + 8 * (s >> 4);            // head 0..47, fixed XCD
    const int q   = s & 15;                        // 0..15
    const int pw  = 2 * q + wave;                  // wave's pair index 0..31

    const size_t base = (size_t)bh * TT * DH;      // Q/K/V all TT*DH per head
    const int b = bh / NH, h = bh % NH;
    us* myP = Ps[wave];

    const f32x4 zero4 = {0.f, 0.f, 0.f, 0.f};

#pragma unroll 1
    for (int seg = 0; seg < 2; ++seg) {
        const int g   = seg ? 63 - pw : pw;        // 32-row group index 0..63
        const int nkt = (g >> 1) + 1;              // key tiles of 64
        const int mA  = g * 32 + l16;              // group A query row
        const int mB  = mA + 16;                   // group B query row

        bf16x8 qfA0 = ld_frag(Qg + base + (size_t)mA * DH + quad * 8);
        bf16x8 qfA1 = ld_frag(Qg + base + (size_t)mA * DH + 32 + quad * 8);
        bf16x8 qfB0 = ld_frag(Qg + base + (size_t)mB * DH + quad * 8);
        bf16x8 qfB1 = ld_frag(Qg + base + (size_t)mB * DH + 32 + quad * 8);

        f32x4 oA[4], oB[4];
#pragma unroll
        for (int i = 0; i < 4; ++i) { oA[i] = zero4; oB[i] = zero4; }
        float lrA = 0.f, lrB = 0.f;   // per-lane partial denominators (deferred reduce)

#pragma unroll 2
        for (int j = 0; j < nkt; ++j) {
            const us* kb = Kg + base + (size_t)j * 4096;   // fraglet tile
            const us* vb = Vt + base + (size_t)j * 4096;

            // K frags: frag (sub,hh) = 1KB contiguous wave-load
            bf16x8 kf[4][2];
#pragma unroll
            for (int sub = 0; sub < 4; ++sub)
#pragma unroll
                for (int hh = 0; hh < 2; ++hh)
                    kf[sub][hh] = ld_frag(kb + sub * 1024 + hh * 512 + lane * 8);

            // S^T = K Q^T for both groups (K frags shared)
            f32x4 sA[4], sB[4];
#pragma unroll
            for (int sub = 0; sub < 4; ++sub) {
                f32x4 t = __builtin_amdgcn_mfma_f32_16x16x32_bf16(kf[sub][0], qfA0, zero4, 0, 0, 0);
                sA[sub]  = __builtin_amdgcn_mfma_f32_16x16x32_bf16(kf[sub][1], qfA1, t, 0, 0, 0);
                f32x4 u = __builtin_amdgcn_mfma_f32_16x16x32_bf16(kf[sub][0], qfB0, zero4, 0, 0, 0);
                sB[sub]  = __builtin_amdgcn_mfma_f32_16x16x32_bf16(kf[sub][1], qfB1, u, 0, 0, 0);
            }

            // V frags: frag (dsub,kc) = 1KB contiguous wave-load
            bf16x8 vf[4][2];
#pragma unroll
            for (int dsub = 0; dsub < 4; ++dsub)
#pragma unroll
                for (int kc = 0; kc < 2; ++kc)
                    vf[dsub][kc] = ld_frag(vb + dsub * 1024 + kc * 512 + lane * 8);

            // diagonal mask on last tile (exp2(-inf) = 0)
            if (j == nkt - 1) {
#pragma unroll
                for (int sub = 0; sub < 4; ++sub)
#pragma unroll
                    for (int reg = 0; reg < 4; ++reg) {
                        int key = j * 64 + sub * 16 + quad * 4 + reg;
                        if (key > mA) sA[sub][reg] = -INFINITY;
                        if (key > mB) sB[sub][reg] = -INFINITY;
                    }
            }

            // fixed-shift softmax, group A: p = exp2(s); per-lane partial sum only
            {
                float rs = 0.f;
#pragma unroll
                for (int sub = 0; sub < 4; ++sub) {
                    float p0 = exp2f(sA[sub][0]), p1 = exp2f(sA[sub][1]);
                    float p2 = exp2f(sA[sub][2]), p3 = exp2f(sA[sub][3]);
                    rs += (p0 + p1) + (p2 + p3);
                    uint2 pk; pk.x = pack2bf(p0, p1); pk.y = pack2bf(p2, p3);
                    *reinterpret_cast<uint2*>(&myP[l16 * PST + sub * 16 + quad * 4]) = pk;
                }
                lrA += rs;
            }
            // group B
            {
                float rs = 0.f;
#pragma unroll
                for (int sub = 0; sub < 4; ++sub) {
                    float p0 = exp2f(sB[sub][0]), p1 = exp2f(sB[sub][1]);
                    float p2 = exp2f(sB[sub][2]), p3 = exp2f(sB[sub][3]);
                    rs += (p0 + p1) + (p2 + p3);
                    uint2 pk; pk.x = pack2bf(p0, p1); pk.y = pack2bf(p2, p3);
                    *reinterpret_cast<uint2*>(&myP[(16 + l16) * PST + sub * 16 + quad * 4]) = pk;
                }
                lrB += rs;
            }

            // O^T += V^T P (V frags shared A/B; same-wave LDS dep -> compiler waits)
#pragma unroll
            for (int kc = 0; kc < 2; ++kc) {
                bf16x8 pfA = *reinterpret_cast<const bf16x8*>(&myP[l16 * PST + kc * 32 + quad * 8]);
                bf16x8 pfB = *reinterpret_cast<const bf16x8*>(&myP[(16 + l16) * PST + kc * 32 + quad * 8]);
#pragma unroll
                for (int d = 0; d < 4; ++d) {
                    oA[d] = __builtin_amdgcn_mfma_f32_16x16x32_bf16(vf[d][kc], pfA, oA[d], 0, 0, 0);
                    oB[d] = __builtin_amdgcn_mfma_f32_16x16x32_bf16(vf[d][kc], pfB, oB[d], 0, 0, 0);
                }
            }
        }

        // deferred cross-quad denominator reduce
        lrA += __shfl_xor(lrA, 16); lrA += __shfl_xor(lrA, 32);
        lrB += __shfl_xor(lrB, 16); lrB += __shfl_xor(lrB, 32);

        // epilogue: O^T[d][m] -> att[b, t=m, h*64+d], 8B packed stores
        const float invA = 1.f / lrA, invB = 1.f / lrB;
        us* orowA = Og + ((size_t)(b * TT + mA)) * CC + h * DH;
        us* orowB = Og + ((size_t)(b * TT + mB)) * CC + h * DH;
#pragma unroll
        for (int d = 0; d < 4; ++d) {
            uint2 pa, pb;
            pa.x = pack2bf(oA[d][0] * invA, oA[d][1] * invA);
            pa.y = pack2bf(oA[d][2] * invA, oA[d][3] * invA);
            pb.x = pack2bf(oB[d][0] * invB, oB[d][1] * invB);
            pb.y = pack2bf(oB[d][2] * invB, oB[d][3] * invB);
            *reinterpret_cast<uint2*>(orowA + d * 16 + quad * 4) = pa;
            *reinterpret_cast<uint2*>(orowB + d * 16 + quad * 4) = pb;
        }
    }
}

// ---------- launch ----------
extern "C" void kernel_launch(void* const* d_in, const int* in_sizes, int n_in,
                              void* d_out, int out_size, void* d_ws, size_t ws_size,
                              hipStream_t stream)
{
    const float* x      = (const float*)d_in[0];
    const float* w_attn = (const float*)d_in[1];
    const float* b_attn = (const float*)d_in[2];
    const float* w_proj = (const float*)d_in[3];
    const float* b_proj = (const float*)d_in[4];
    float* out = (float*)d_out;

    char* ws = (char*)d_ws;
    size_t off = 0;
    auto alloc = [&](size_t bytes) {
        void* p = ws + off;
        off += (bytes + 255) & ~(size_t)255;
        return p;
    };
    us* wtA = (us*)alloc((size_t)(3 * CC) * CC * 2);  // [2304][768] bf16
    us* wtP = (us*)alloc((size_t)CC * CC * 2);        // [768][768]  bf16
    us* xb  = (us*)alloc((size_t)MM * CC * 2);        // x as bf16
    us* Qb  = (us*)alloc((size_t)MM * CC * 2);        // [B,H,T,D]
    us* Kb  = (us*)alloc((size_t)MM * CC * 2);        // K fraglet
    us* Vtb = (us*)alloc((size_t)MM * CC * 2);        // V fraglet
    us* att = (us*)alloc((size_t)MM * CC * 2);        // [B,T,C]

    prep_k<<<PREP_CAST_BLK + PREP_TA_BLK + PREP_TP_BLK, 256, 0, stream>>>(
        x, xb, w_attn, wtA, w_proj, wtP);

    gemm_bt<1><<<dim3((3 * CC) / BN * (MM / BM)), 256, 0, stream>>>(
        xb, wtA, b_attn, nullptr, Qb, Kb, Vtb, MM, 3 * CC, CC);

    attn_k<<<dim3(16 * BB * NH), 128, 0, stream>>>(Qb, Kb, Vtb, att);

    gemm_bt<0><<<dim3((CC / BN) * (MM / BM)), 256, 0, stream>>>(
        att, wtP, b_proj, out, nullptr, nullptr, nullptr, MM, CC, CC);

    (void)in_sizes; (void)n_in; (void)out_size; (void)ws_size;
}

// Round 14
// 218.735 us; speedup vs baseline: 1.0562x; 1.0562x over previous
//
#include <hip/hip_runtime.h>
#include <cstdint>
#include <cstddef>

// ---------- types / helpers ----------
typedef __bf16 bf16x8 __attribute__((ext_vector_type(8)));
typedef float  f32x4  __attribute__((ext_vector_type(4)));
typedef unsigned short us;

#define DEV static __device__ __forceinline__

DEV us f2bf(float f) {
    unsigned int u = __builtin_bit_cast(unsigned int, f);
    u += 0x7FFFu + ((u >> 16) & 1u);   // RNE
    return (us)(u >> 16);
}
DEV unsigned int pack2bf(float a, float b) {   // [lo=a, hi=b], round-half-up (cheap)
    unsigned int ua = __builtin_bit_cast(unsigned int, a) + 0x8000u;
    unsigned int ub = __builtin_bit_cast(unsigned int, b) + 0x8000u;
    return (ua >> 16) | (ub & 0xFFFF0000u);    // -> v_perm_b32
}

DEV void gll16(const void* g, void* l) {   // 16B global->LDS direct (wave: +lane*16)
    __builtin_amdgcn_global_load_lds(
        (const __attribute__((address_space(1))) unsigned int*)g,
        (__attribute__((address_space(3))) unsigned int*)l, 16, 0, 0);
}

DEV bf16x8 ld_frag(const us* p) {
    return __builtin_bit_cast(bf16x8, *reinterpret_cast<const uint4*>(p));
}

// ---------- problem constants ----------
#define BB 4
#define TT 2048
#define CC 768
#define NH 12
#define DH 64
#define MM (BB*TT)          // 8192
#define QSCALE 0.1803368801111144f   // 0.125 * log2(e): softmax via exp2

// ---------- fused prep: cast x->bf16 | transpose w_attn | transpose w_proj ----------
#define PREP_CAST_BLK 1024
#define PREP_TA_BLK   ((3*CC/32)*(CC/32))   // 72*24 = 1728
#define PREP_TP_BLK   ((CC/32)*(CC/32))     // 24*24 = 576

__global__ __launch_bounds__(256)
void prep_k(const float* __restrict__ x, us* __restrict__ xb,
            const float* __restrict__ wA, us* __restrict__ wAt,
            const float* __restrict__ wP, us* __restrict__ wPt)
{
    const int bid = blockIdx.x;
    const int tid = threadIdx.x;

    if (bid < PREP_CAST_BLK) {
        const int n4 = MM * CC / 4;
        int i = bid * 256 + tid;
        const int stride = PREP_CAST_BLK * 256;
        for (; i < n4; i += stride) {
            float4 f = reinterpret_cast<const float4*>(x)[i];
            ushort4 o;
            o.x = f2bf(f.x); o.y = f2bf(f.y); o.z = f2bf(f.z); o.w = f2bf(f.w);
            reinterpret_cast<ushort4*>(xb)[i] = o;
        }
        return;
    }

    // transpose path: dst[Cc][R] = bf16(src[R][Cc]), 32x32 tiles, threads (32,8)
    __shared__ float tile[32][33];
    const float* src; us* dst; int R, Cc, tb;
    if (bid < PREP_CAST_BLK + PREP_TA_BLK) {
        src = wA; dst = wAt; R = CC; Cc = 3 * CC; tb = bid - PREP_CAST_BLK;
    } else {
        src = wP; dst = wPt; R = CC; Cc = CC;     tb = bid - PREP_CAST_BLK - PREP_TA_BLK;
    }
    const int gx = Cc / 32;
    const int c0 = (tb % gx) * 32, r0 = (tb / gx) * 32;
    const int tx = tid & 31, ty = tid >> 5;
#pragma unroll
    for (int i = 0; i < 4; ++i)
        tile[ty + i*8][tx] = src[(size_t)(r0 + ty + i*8) * Cc + c0 + tx];
    __syncthreads();
#pragma unroll
    for (int i = 0; i < 4; ++i)
        dst[(size_t)(c0 + ty + i*8) * R + r0 + tx] = f2bf(tile[tx][ty + i*8]);
}

// ---------- fraglet layouts ----------
// K: offK(t,d) = (t>>4)*1024 + ((d>>3)&7)*128 + (t&15)*8 + (d&7)
//    frag (j,sub,hh): addr = (j*4+sub)*1024 + hh*512 + lane*8
// V: offV(d,t) = (t>>6)*4096 + ((d>>4)&3)*1024 + ((t>>3)&7)*128 + (d&15)*8 + (t&7)
//    frag (j,dsub,kc): addr = j*4096 + dsub*1024 + kc*512 + lane*8
// Both bijective on [0, TT*DH).

// ---------- GEMM: C[M,N] = A[M,K](bf16) * Bt[N,K]^T + bias[N] ----------
// 2-phase double-buffered staging + XCD-chunked block swizzle (kept from R12:
// inferred -2.6us). MODE 0: f32 Cout | MODE 1: scatter Q / K-fraglet / V-fraglet
#define BM 128
#define BN 128
#define BK 32

template<int MODE>
__global__ __launch_bounds__(256)
void gemm_bt(const us* __restrict__ A,
             const us* __restrict__ Bt,
             const float* __restrict__ bias,
             float* __restrict__ Cout,
             us* __restrict__ Qo, us* __restrict__ Ko, us* __restrict__ Vo,
             int M, int N, int K)
{
    __shared__ __align__(16) us As[2][BM * BK];
    __shared__ __align__(16) us Bs[2][BN * BK];

    const int tid  = threadIdx.x;
    const int wave = tid >> 6, lane = tid & 63;
    const int quad = lane >> 4, l16 = lane & 15;
    const int waveM = (wave >> 1) * 64, waveN = (wave & 1) * 64;

    // XCD-chunked swizzle (bijective: gridDim.x % 8 == 0)
    const int nxt   = N / BN;
    const int chunk = gridDim.x >> 3;
    const int lid   = blockIdx.x;
    const int swz   = (lid & 7) * chunk + (lid >> 3);
    const int m0 = (swz / nxt) * BM, n0 = (swz % nxt) * BN;

    const f32x4 zero4 = {0.f, 0.f, 0.f, 0.f};
    f32x4 acc[4][4];
#pragma unroll
    for (int i = 0; i < 4; ++i)
#pragma unroll
        for (int j = 0; j < 4; ++j) acc[i][j] = zero4;

    const int lrow = lane >> 2, lch = (lane & 3) * 8;
    const int nk = K / BK;

    auto STAGE = [&](int buf, int kt) {
#pragma unroll
        for (int c = 0; c < 2; ++c) {
            int rb = (wave * 2 + c) * 16;
            int row = rb + lrow;
            gll16(A  + (size_t)(m0 + row) * K + kt * BK + lch, &As[buf][rb * BK]);
            gll16(Bt + (size_t)(n0 + row) * K + kt * BK + lch, &Bs[buf][rb * BK]);
        }
    };

    STAGE(0, 0);
    __syncthreads();                    // vmcnt(0) drain: buf0 ready
    int cur = 0;

    for (int kt = 0; kt < nk; ++kt) {
        if (kt + 1 < nk) STAGE(cur ^ 1, kt + 1);   // prefetch into other buffer

        bf16x8 af[4], bfv[4];
#pragma unroll
        for (int mi = 0; mi < 4; ++mi)
            af[mi] = *reinterpret_cast<const bf16x8*>(&As[cur][(waveM + mi * 16 + l16) * BK + quad * 8]);
#pragma unroll
        for (int ni = 0; ni < 4; ++ni)
            bfv[ni] = *reinterpret_cast<const bf16x8*>(&Bs[cur][(waveN + ni * 16 + l16) * BK + quad * 8]);
#pragma unroll
        for (int mi = 0; mi < 4; ++mi)
#pragma unroll
            for (int ni = 0; ni < 4; ++ni)
                acc[mi][ni] = __builtin_amdgcn_mfma_f32_16x16x32_bf16(af[mi], bfv[ni], acc[mi][ni], 0, 0, 0);

        __syncthreads();
        cur ^= 1;
    }

    // epilogue: C/D layout col = l16, row = quad*4 + reg
#pragma unroll
    for (int mi = 0; mi < 4; ++mi) {
#pragma unroll
        for (int ni = 0; ni < 4; ++ni) {
            int n = n0 + waveN + ni * 16 + l16;
            float bv = bias[n];
            int mg = m0 + waveM + mi * 16 + quad * 4;   // first of 4 consecutive m
            if (MODE == 0) {
#pragma unroll
                for (int reg = 0; reg < 4; ++reg)
                    Cout[(size_t)(mg + reg) * N + n] = acc[mi][ni][reg] + bv;
            } else {
                int which = n / CC, c2 = n % CC;
                int h = c2 >> 6, d = c2 & 63;
                int b = mg >> 11, t0 = mg & 2047;
                size_t hb = (size_t)(b * NH + h) * TT * DH;
                if (which == 2) {
                    // V fraglet: 4 consecutive t stay contiguous -> one 8B store
                    size_t off = hb + (size_t)(t0 >> 6) * 4096 + (d >> 4) * 1024
                               + ((t0 >> 3) & 7) * 128 + (d & 15) * 8 + (t0 & 7);
                    ushort4 pk;
                    pk.x = f2bf(acc[mi][ni][0] + bv);
                    pk.y = f2bf(acc[mi][ni][1] + bv);
                    pk.z = f2bf(acc[mi][ni][2] + bv);
                    pk.w = f2bf(acc[mi][ni][3] + bv);
                    *reinterpret_cast<ushort4*>(Vo + off) = pk;
                } else if (which == 1) {
                    // K fraglet: per-reg scalar store, stride 8 elems
                    size_t off = hb + (size_t)(t0 >> 4) * 1024 + (d >> 3) * 128
                               + (t0 & 15) * 8 + (d & 7);
#pragma unroll
                    for (int reg = 0; reg < 4; ++reg)
                        Ko[off + reg * 8] = f2bf(acc[mi][ni][reg] + bv);
                } else {
#pragma unroll
                    for (int reg = 0; reg < 4; ++reg) {
                        size_t off = hb + (size_t)(t0 + reg) * DH + d;
                        Qo[off] = f2bf((acc[mi][ni][reg] + bv) * QSCALE);
                    }
                }
            }
        }
    }
}

// ---------- flash attention: R11 verified path + setprio around MFMA clusters ----------
// 768 blocks x 2 waves, pair {pw,63-pw}, 33 tiles/wave, fraglet loads,
// fixed-shift softmax, deferred l-reduce, P LDS round-trip. EXACT R11 code
// (74.2us verified; R8/R9/R12/R13 all regressed) + T5 s_setprio(1) around the
// MFMA clusters. Regime matches the catalog's attn-positive case (m191:
// independent waves, no barriers, +4-7%), NOT the GEMM-lockstep null (m190).
#define PST 72

__global__ __launch_bounds__(128)
void attn_k(const us* __restrict__ Qg,
            const us* __restrict__ Kg,   // fraglet layout
            const us* __restrict__ Vt,   // fraglet layout
            us* __restrict__ Og)
{
    __shared__ __align__(16) us Ps[2][32 * PST];   // per-wave P[g*16+m][key]

    const int tid  = threadIdx.x;
    const int wave = tid >> 6, lane = tid & 63;
    const int quad = lane >> 4, l16 = lane & 15;

    // XCD-locality decode: xcd = id%8 (round-robin dispatch heuristic)
    const int id  = blockIdx.x;
    const int xcd = id & 7, s = id >> 3;           // s in 0..95
    const int bh  = xcd + 8 * (s >> 4);            // head 0..47, fixed XCD
    const int q   = s & 15;                        // 0..15
    const int pw  = 2 * q + wave;                  // wave's pair index 0..31

    const size_t base = (size_t)bh * TT * DH;      // Q/K/V all TT*DH per head
    const int b = bh / NH, h = bh % NH;
    us* myP = Ps[wave];

    const f32x4 zero4 = {0.f, 0.f, 0.f, 0.f};

#pragma unroll 1
    for (int seg = 0; seg < 2; ++seg) {
        const int g   = seg ? 63 - pw : pw;        // 32-row group index 0..63
        const int nkt = (g >> 1) + 1;              // key tiles of 64
        const int mA  = g * 32 + l16;              // group A query row
        const int mB  = mA + 16;                   // group B query row

        bf16x8 qfA0 = ld_frag(Qg + base + (size_t)mA * DH + quad * 8);
        bf16x8 qfA1 = ld_frag(Qg + base + (size_t)mA * DH + 32 + quad * 8);
        bf16x8 qfB0 = ld_frag(Qg + base + (size_t)mB * DH + quad * 8);
        bf16x8 qfB1 = ld_frag(Qg + base + (size_t)mB * DH + 32 + quad * 8);

        f32x4 oA[4], oB[4];
#pragma unroll
        for (int i = 0; i < 4; ++i) { oA[i] = zero4; oB[i] = zero4; }
        float lrA = 0.f, lrB = 0.f;   // per-lane partial denominators (deferred reduce)

#pragma unroll 1
        for (int j = 0; j < nkt; ++j) {
            const us* kb = Kg + base + (size_t)j * 4096;   // fraglet tile
            const us* vb = Vt + base + (size_t)j * 4096;

            // K frags: frag (sub,hh) = 1KB contiguous wave-load
            bf16x8 kf[4][2];
#pragma unroll
            for (int sub = 0; sub < 4; ++sub)
#pragma unroll
                for (int hh = 0; hh < 2; ++hh)
                    kf[sub][hh] = ld_frag(kb + sub * 1024 + hh * 512 + lane * 8);

            // S^T = K Q^T for both groups (K frags shared) — priority-boosted
            f32x4 sA[4], sB[4];
            __builtin_amdgcn_s_setprio(1);
#pragma unroll
            for (int sub = 0; sub < 4; ++sub) {
                f32x4 t = __builtin_amdgcn_mfma_f32_16x16x32_bf16(kf[sub][0], qfA0, zero4, 0, 0, 0);
                sA[sub]  = __builtin_amdgcn_mfma_f32_16x16x32_bf16(kf[sub][1], qfA1, t, 0, 0, 0);
                f32x4 u = __builtin_amdgcn_mfma_f32_16x16x32_bf16(kf[sub][0], qfB0, zero4, 0, 0, 0);
                sB[sub]  = __builtin_amdgcn_mfma_f32_16x16x32_bf16(kf[sub][1], qfB1, u, 0, 0, 0);
            }
            __builtin_amdgcn_s_setprio(0);

            // V frags: frag (dsub,kc) = 1KB contiguous wave-load
            bf16x8 vf[4][2];
#pragma unroll
            for (int dsub = 0; dsub < 4; ++dsub)
#pragma unroll
                for (int kc = 0; kc < 2; ++kc)
                    vf[dsub][kc] = ld_frag(vb + dsub * 1024 + kc * 512 + lane * 8);

            // diagonal mask on last tile (exp2(-inf) = 0)
            if (j == nkt - 1) {
#pragma unroll
                for (int sub = 0; sub < 4; ++sub)
#pragma unroll
                    for (int reg = 0; reg < 4; ++reg) {
                        int key = j * 64 + sub * 16 + quad * 4 + reg;
                        if (key > mA) sA[sub][reg] = -INFINITY;
                        if (key > mB) sB[sub][reg] = -INFINITY;
                    }
            }

            // fixed-shift softmax, group A: p = exp2(s); per-lane partial sum only
            {
                float rs = 0.f;
#pragma unroll
                for (int sub = 0; sub < 4; ++sub) {
                    float p0 = exp2f(sA[sub][0]), p1 = exp2f(sA[sub][1]);
                    float p2 = exp2f(sA[sub][2]), p3 = exp2f(sA[sub][3]);
                    rs += (p0 + p1) + (p2 + p3);
                    uint2 pk; pk.x = pack2bf(p0, p1); pk.y = pack2bf(p2, p3);
                    *reinterpret_cast<uint2*>(&myP[l16 * PST + sub * 16 + quad * 4]) = pk;
                }
                lrA += rs;
            }
            // group B
            {
                float rs = 0.f;
#pragma unroll
                for (int sub = 0; sub < 4; ++sub) {
                    float p0 = exp2f(sB[sub][0]), p1 = exp2f(sB[sub][1]);
                    float p2 = exp2f(sB[sub][2]), p3 = exp2f(sB[sub][3]);
                    rs += (p0 + p1) + (p2 + p3);
                    uint2 pk; pk.x = pack2bf(p0, p1); pk.y = pack2bf(p2, p3);
                    *reinterpret_cast<uint2*>(&myP[(16 + l16) * PST + sub * 16 + quad * 4]) = pk;
                }
                lrB += rs;
            }

            // O^T += V^T P (V frags shared A/B; same-wave LDS dep) — priority-boosted
            __builtin_amdgcn_s_setprio(1);
#pragma unroll
            for (int kc = 0; kc < 2; ++kc) {
                bf16x8 pfA = *reinterpret_cast<const bf16x8*>(&myP[l16 * PST + kc * 32 + quad * 8]);
                bf16x8 pfB = *reinterpret_cast<const bf16x8*>(&myP[(16 + l16) * PST + kc * 32 + quad * 8]);
#pragma unroll
                for (int d = 0; d < 4; ++d) {
                    oA[d] = __builtin_amdgcn_mfma_f32_16x16x32_bf16(vf[d][kc], pfA, oA[d], 0, 0, 0);
                    oB[d] = __builtin_amdgcn_mfma_f32_16x16x32_bf16(vf[d][kc], pfB, oB[d], 0, 0, 0);
                }
            }
            __builtin_amdgcn_s_setprio(0);
        }

        // deferred cross-quad denominator reduce
        lrA += __shfl_xor(lrA, 16); lrA += __shfl_xor(lrA, 32);
        lrB += __shfl_xor(lrB, 16); lrB += __shfl_xor(lrB, 32);

        // epilogue: O^T[d][m] -> att[b, t=m, h*64+d], 8B packed stores
        const float invA = 1.f / lrA, invB = 1.f / lrB;
        us* orowA = Og + ((size_t)(b * TT + mA)) * CC + h * DH;
        us* orowB = Og + ((size_t)(b * TT + mB)) * CC + h * DH;
#pragma unroll
        for (int d = 0; d < 4; ++d) {
            uint2 pa, pb;
            pa.x = pack2bf(oA[d][0] * invA, oA[d][1] * invA);
            pa.y = pack2bf(oA[d][2] * invA, oA[d][3] * invA);
            pb.x = pack2bf(oB[d][0] * invB, oB[d][1] * invB);
            pb.y = pack2bf(oB[d][2] * invB, oB[d][3] * invB);
            *reinterpret_cast<uint2*>(orowA + d * 16 + quad * 4) = pa;
            *reinterpret_cast<uint2*>(orowB + d * 16 + quad * 4) = pb;
        }
    }
}

// ---------- launch ----------
extern "C" void kernel_launch(void* const* d_in, const int* in_sizes, int n_in,
                              void* d_out, int out_size, void* d_ws, size_t ws_size,
                              hipStream_t stream)
{
    const float* x      = (const float*)d_in[0];
    const float* w_attn = (const float*)d_in[1];
    const float* b_attn = (const float*)d_in[2];
    const float* w_proj = (const float*)d_in[3];
    const float* b_proj = (const float*)d_in[4];
    float* out = (float*)d_out;

    char* ws = (char*)d_ws;
    size_t off = 0;
    auto alloc = [&](size_t bytes) {
        void* p = ws + off;
        off += (bytes + 255) & ~(size_t)255;
        return p;
    };
    us* wtA = (us*)alloc((size_t)(3 * CC) * CC * 2);  // [2304][768] bf16
    us* wtP = (us*)alloc((size_t)CC * CC * 2);        // [768][768]  bf16
    us* xb  = (us*)alloc((size_t)MM * CC * 2);        // x as bf16
    us* Qb  = (us*)alloc((size_t)MM * CC * 2);        // [B,H,T,D]
    us* Kb  = (us*)alloc((size_t)MM * CC * 2);        // K fraglet
    us* Vtb = (us*)alloc((size_t)MM * CC * 2);        // V fraglet
    us* att = (us*)alloc((size_t)MM * CC * 2);        // [B,T,C]

    prep_k<<<PREP_CAST_BLK + PREP_TA_BLK + PREP_TP_BLK, 256, 0, stream>>>(
        x, xb, w_attn, wtA, w_proj, wtP);

    gemm_bt<1><<<dim3((3 * CC) / BN * (MM / BM)), 256, 0, stream>>>(
        xb, wtA, b_attn, nullptr, Qb, Kb, Vtb, MM, 3 * CC, CC);

    attn_k<<<dim3(16 * BB * NH), 128, 0, stream>>>(Qb, Kb, Vtb, att);

    gemm_bt<0><<<dim3((CC / BN) * (MM / BM)), 256, 0, stream>>>(
        att, wtP, b_proj, out, nullptr, nullptr, nullptr, MM, CC, CC);

    (void)in_sizes; (void)n_in; (void)out_size; (void)ws_size;
}